// Round 3
// baseline (130.054 us; speedup 1.0000x reference)
//
#include <hip/hip_runtime.h>
#include <hip/hip_bf16.h>
#include <math.h>

typedef __attribute__((ext_vector_type(8))) short  short8;
typedef __attribute__((ext_vector_type(4))) float  float4v;

#define NE 64
#define FLAG_CAP 8192
#define EPS_TIE 2e-4f
#define TOKB 64

#define BARRIER  asm volatile("s_barrier" ::: "memory")
#define WAITV(n) asm volatile("s_waitcnt vmcnt(" #n ")" ::: "memory")

__device__ __forceinline__ unsigned short f2bf(float x){
  unsigned u = __float_as_uint(x);
  return (unsigned short)((u + 0x7fffu + ((u>>16)&1u)) >> 16);
}
__device__ __forceinline__ float bf2f(unsigned short h){
  return __uint_as_float(((unsigned)h)<<16);
}
__device__ __forceinline__ float warp_sum64(float v){
  #pragma unroll
  for (int off=1; off<64; off<<=1) v += __shfl_xor(v, off, 64);
  return v;
}

// async global->LDS, 16B per lane: dest = lds_base(uniform) + lane*16
__device__ __forceinline__ void gld16(void* lds, const void* g){
  __builtin_amdgcn_global_load_lds(
      (const __attribute__((address_space(1))) unsigned int*)g,
      (__attribute__((address_space(3))) unsigned int*)lds,
      16, 0, 0);
}

// ---------- kernel 1: split W into bf16 hi/lo in MFMA B-frag order (+zero stats) ----------
// frag layout: [ks][te][lane][8]; lane l -> e = te*16 + (l&15), k = ks*32 + (l>>4)*8 + j
__global__ __launch_bounds__(256) void prep_w(
    const float* __restrict__ W, unsigned short* __restrict__ whi,
    unsigned short* __restrict__ wlo, float* __restrict__ zbuf, int K)
{
  if (blockIdx.x == 0){                       // zero imp8[512]+cnt8[512]+flagCnt
    #pragma unroll
    for (int i=0;i<5;++i){
      const int idx = threadIdx.x + i*256;
      if (idx < 1025) zbuf[idx] = 0.f;
    }
  }
  const int id = blockIdx.x*256 + threadIdx.x;
  const int nfrag = (K/32)*4*64;
  if (id >= nfrag) return;
  const int lane = id & 63, te = (id>>6)&3, ks = id>>8;
  const int e  = te*16 + (lane&15);
  const int k0 = ks*32 + ((lane>>4)<<3);
  const float* src = W + (size_t)e*K + k0;
  short8 h8, l8;
  #pragma unroll
  for (int j=0;j<8;++j){
    float x = src[j];
    unsigned short hb = f2bf(x);
    h8[j] = (short)hb;
    l8[j] = (short)f2bf(x - bf2f(hb));
  }
  const size_t off = (size_t)id*8;
  *(short8*)(whi + off) = h8;
  *(short8*)(wlo + off) = l8;
}

// ---------- bf16 hi/lo conversion via packed cvt ----------
__device__ __forceinline__ void cvt8b(const float4& c, const float4& d,
                                      short8& hi, short8& lo){
  const float f[8] = {c.x,c.y,c.z,c.w,d.x,d.y,d.z,d.w};
  union { short8 s; unsigned u[4]; } H, L;
  #pragma unroll
  for (int p=0;p<4;++p){
    float2 v = make_float2(f[2*p], f[2*p+1]);
    __hip_bfloat162 hb = __float22bfloat162_rn(v);
    H.u[p] = *reinterpret_cast<unsigned*>(&hb);
    float2 back = __bfloat1622float2(hb);
    float2 res = make_float2(v.x - back.x, v.y - back.y);
    __hip_bfloat162 lb = __float22bfloat162_rn(res);
    L.u[p] = *reinterpret_cast<unsigned*>(&lb);
  }
  hi = H.s; lo = L.s;
}

#define MFMA3(AH, AL, BH, BL, ACC)                                          \
  ACC = __builtin_amdgcn_mfma_f32_16x16x32_bf16(AH, BH, ACC, 0,0,0);        \
  ACC = __builtin_amdgcn_mfma_f32_16x16x32_bf16(AH, BL, ACC, 0,0,0);        \
  ACC = __builtin_amdgcn_mfma_f32_16x16x32_bf16(AL, BH, ACC, 0,0,0);

// ---------- kernel 2: FUSED full-K GEMM + router finish ----------
// 64 tokens/block, 8 waves; wave w = (token quarter th=w>>1) x (expert half eh=w&1).
// Full K in one block (128 tiles of BK=32, depth-3 pipeline, counted vmcnt) ->
// logits never touch HBM; finish runs in-block on LDS logits.
__global__ __launch_bounds__(512) void gemm_router(
    const float* __restrict__ hp, const unsigned short* __restrict__ whi,
    const unsigned short* __restrict__ wlo, const float* __restrict__ bp,
    float* __restrict__ outp, float* __restrict__ imp8, float* __restrict__ cnt8,
    int* __restrict__ flagCnt, int* __restrict__ flagList, int K, long M, int tiles)
{
  __shared__ float          As[3][TOKB*32];   // 3 x 8 KB
  __shared__ unsigned short Bs[3][8*512];     // 3 x 8 KB
  __shared__ float          lg[TOKB][NE];     // 16 KB logits
  __shared__ float          red[2][8][64];    // 4 KB stats reduce

  const int tid = threadIdx.x;
  const int l = tid & 63, w = tid >> 6;
  const int tok0 = blockIdx.x * TOKB;
  const int r16 = l & 15, kg = l >> 4;
  const int th = w >> 1;            // token quarter: rows th*16 .. th*16+15
  const int eh = w & 1;             // expert half: te in {eh*2, eh*2+1}

  float4v acc[2];
  acc[0] = (float4v){0.f,0.f,0.f,0.f};
  acc[1] = (float4v){0.f,0.f,0.f,0.f};

  const unsigned short* bsel[2] = { whi, wlo };
  const int srcblkA = (l&7) ^ (l>>3);        // pre-swizzled source 16B-block

  auto STAGE = [&](int buf, int t){
    // A: wave w stages rows w*8 .. w*8+7 (1 KB)
    const int row = w*8 + (l>>3);
    const float* srcA = hp + (size_t)(tok0 + row)*K + t*32 + (srcblkA<<2);
    gld16((void*)(As[buf] + w*256), (const void*)srcA);
    // B: unit u = w -> (te = w>>1, d = w&1)
    const unsigned short* srcB = bsel[w & 1]
        + (size_t)t*2048 + (w>>1)*512 + (size_t)l*8;
    gld16((void*)(Bs[buf] + w*512), (const void*)srcB);
  };

  auto COMPUTE = [&](int buf){
    short8 Bh[2], Bl[2];                     // B once per tile -> regs
    #pragma unroll
    for (int lt=0; lt<2; ++lt){
      const int te = eh*2 + lt;
      Bh[lt] = *(const short8*)(Bs[buf] + (te*2+0)*512 + l*8);
      Bl[lt] = *(const short8*)(Bs[buf] + (te*2+1)*512 + l*8);
    }
    const float* arow = As[buf] + (th*16 + r16)*32;
    const int c0 = kg*2, sw = r16 & 7;
    float4 a0 = *(const float4*)(arow + (((c0  ) ^ sw) << 2));
    float4 a1 = *(const float4*)(arow + (((c0+1) ^ sw) << 2));
    short8 Ah, Al;
    cvt8b(a0, a1, Ah, Al);
    #pragma unroll
    for (int lt=0; lt<2; ++lt){
      MFMA3(Ah, Al, Bh[lt], Bl[lt], acc[lt]);
    }
  };

  STAGE(0,0); STAGE(1,1); STAGE(2,2);
  WAITV(4); BARRIER;                 // tile0 landed; tiles 1,2 flying
  int t = 0;
  for (; t < tiles-3; ++t){
    const int b = t % 3;
    COMPUTE(b);
    BARRIER;                         // all waves done reading buf b
    STAGE(b, t+3);                   // 6 outstanding/wave
    WAITV(4); BARRIER;               // tile t+1 landed; t+2,t+3 flying
  }
  COMPUTE(t%3);
  WAITV(2); BARRIER;                 // tile tiles-2 landed
  COMPUTE((t+1)%3);
  WAITV(0); BARRIER;                 // tile tiles-1 landed
  COMPUTE((t+2)%3);

  // ---- epilogue: logits -> LDS (C layout m89: col=lane&15, row=(lane>>4)*4+reg)
  #pragma unroll
  for (int lt=0; lt<2; ++lt)
    #pragma unroll
    for (int r=0; r<4; ++r)
      lg[th*16 + (kg<<2) + r][(eh*2+lt)*16 + r16] = acc[lt][r];
  __syncthreads();

  // ---- finish: wave w owns tokens w*8 .. w*8+7; lane = expert
  const float bias = bp[l];
  float impL = 0.f, cntL = 0.f;
  #pragma unroll 1
  for (int it=0; it<8; ++it){
    const int  tl = w*8 + it;
    const long tg = (long)tok0 + tl;
    float v = lg[tl][l] + bias;
    float m1 = v; int i1 = l;
    #pragma unroll
    for (int off=1; off<64; off<<=1){
      float ov = __shfl_xor(m1, off, 64);
      int   oi = __shfl_xor(i1, off, 64);
      if (ov > m1 || (ov == m1 && oi < i1)){ m1 = ov; i1 = oi; }
    }
    float vm = (l == i1) ? -3.4e38f : v;
    float m2 = vm; int i2 = l;
    #pragma unroll
    for (int off=1; off<64; off<<=1){
      float ov = __shfl_xor(m2, off, 64);
      int   oi = __shfl_xor(i2, off, 64);
      if (ov > m2 || (ov == m2 && oi < i2)){ m2 = ov; i2 = oi; }
    }
    float vm3 = (l==i1 || l==i2) ? -3.4e38f : v;
    float m3 = vm3;
    #pragma unroll
    for (int off=1; off<64; off<<=1) m3 = fmaxf(m3, __shfl_xor(m3, off, 64));
    if ((m2 - m3) < EPS_TIE && l == 0){
      int idx = atomicAdd(flagCnt, 1);
      if (idx < FLAG_CAP) flagList[idx] = (int)tg;
    }
    const float ex = __expf(m2 - m1);
    const float s1 = 1.f / (1.f + ex);
    const float s2 = ex * s1;
    const float p = __expf(v - m1);
    const float S = warp_sum64(p);
    impL += p / S;
    const float rw = (l==i1) ? s1 : ((l==i2) ? s2 : 0.f);
    outp[(size_t)tg*NE + l] = rw;
    if (l==i1 || l==i2) cntL += 1.f;
  }
  red[0][w][l] = impL;
  red[1][w][l] = cntL;
  __syncthreads();
  if (tid < 64){
    float s = 0.f, c = 0.f;
    #pragma unroll
    for (int q=0; q<8; ++q){ s += red[0][q][tid]; c += red[1][q][tid]; }
    const int g = (blockIdx.x & 7) << 6;   // 8 banks kill atomic serialization
    atomicAdd(&imp8[g + tid], s);
    atomicAdd(&cnt8[g + tid], c);
  }
}

// ---------- kernel 3: fixup (one token per block) + aux fold (block 0) ----------
__global__ __launch_bounds__(256) void fixup_aux(
    const float* __restrict__ hp, const float* __restrict__ Wp,
    const float* __restrict__ bp, float* __restrict__ outp,
    const int* __restrict__ flagCnt, const int* __restrict__ flagList,
    const float* __restrict__ imp8, const float* __restrict__ cnt8,
    float* __restrict__ auxp, float scale, int K)
{
  __shared__ float hrow[4096];
  __shared__ float lg[NE];
  if (blockIdx.x == 0 && threadIdx.x < 64){     // aux: imp/cnt ready (prev kernel)
    float s = 0.f, c = 0.f;
    #pragma unroll
    for (int g=0; g<8; ++g){
      s += imp8[(g<<6) + threadIdx.x];
      c += cnt8[(g<<6) + threadIdx.x];
    }
    float v = s * c;
    v = warp_sum64(v);
    if (threadIdx.x == 0) auxp[0] = v * scale;
  }
  int n = *flagCnt; if (n > FLAG_CAP) n = FLAG_CAP;
  const int e   = threadIdx.x >> 2;
  const int sub = threadIdx.x & 3;
  const int lane = threadIdx.x & 63;

  for (int f = blockIdx.x; f < n; f += gridDim.x){
    const int tok = flagList[f];
    const float* hr = hp + (size_t)tok*K;
    #pragma unroll
    for (int c=0; c<4; ++c){
      const int idx = threadIdx.x*4 + c*1024;
      *(float4*)&hrow[idx] = *(const float4*)(hr + idx);
    }
    __syncthreads();
    const float* wr = Wp + (size_t)e*K;
    float s = 0.f;
    for (int it=0; it<64; ++it){
      const int k0 = it*64 + sub*16;
      #pragma unroll
      for (int u=0; u<4; ++u){
        float4 wv = *(const float4*)(wr + k0 + u*4);
        float4 hv = *(const float4*)(&hrow[k0 + u*4]);
        s = fmaf(hv.x, wv.x, s); s = fmaf(hv.y, wv.y, s);
        s = fmaf(hv.z, wv.z, s); s = fmaf(hv.w, wv.w, s);
      }
    }
    s += __shfl_xor(s, 1, 64);
    s += __shfl_xor(s, 2, 64);
    if (sub == 0) lg[e] = s + bp[e];
    __syncthreads();
    if (threadIdx.x < 64){
      const float v = lg[lane];
      float m1 = v; int i1 = lane;
      #pragma unroll
      for (int off=1; off<64; off<<=1){
        float ov = __shfl_xor(m1, off, 64);
        int   oi = __shfl_xor(i1, off, 64);
        if (ov > m1 || (ov == m1 && oi < i1)){ m1 = ov; i1 = oi; }
      }
      float vm = (lane == i1) ? -3.4e38f : v;
      float m2 = vm; int i2 = lane;
      #pragma unroll
      for (int off=1; off<64; off<<=1){
        float ov = __shfl_xor(m2, off, 64);
        int   oi = __shfl_xor(i2, off, 64);
        if (ov > m2 || (ov == m2 && oi < i2)){ m2 = ov; i2 = oi; }
      }
      const float ex = __expf(m2 - m1);
      const float s1 = 1.f / (1.f + ex);
      const float s2 = ex * s1;
      const float rw = (lane==i1) ? s1 : ((lane==i2) ? s2 : 0.f);
      outp[(size_t)tok * NE + lane] = rw;
    }
    __syncthreads();
  }
}

extern "C" void kernel_launch(void* const* d_in, const int* in_sizes, int n_in,
                              void* d_out, int out_size, void* d_ws, size_t ws_size,
                              hipStream_t stream){
  const float* hp = (const float*)d_in[0];
  const float* Wp = (const float*)d_in[1];
  const float* bp = (const float*)d_in[2];
  const int  E = in_sizes[2];               // 64
  const int  K = in_sizes[1] / E;           // 4096
  const long M = (long)in_sizes[0] / K;     // 16384

  float* outp = (float*)d_out;
  float* auxp = outp + (size_t)M * E;

  char* ws = (char*)d_ws;
  float* imp8     = (float*)(ws + 0);        // 8 x 64 f
  float* cnt8     = (float*)(ws + 2048);     // 8 x 64 f
  int*   flagCnt  = (int*)  (ws + 4096);
  int*   flagList = (int*)  (ws + 4160);     // FLAG_CAP ints
  unsigned short* whi = (unsigned short*)(ws + 65536);            // 512 KB
  unsigned short* wlo = (unsigned short*)(ws + 65536 + 524288);   // 512 KB

  const int nfragBlocks = ((K/32)*4*64 + 255)/256;
  const int tiles = K / 32;                 // 128 tiles of BK=32, full K per block

  prep_w<<<dim3(nfragBlocks), dim3(256), 0, stream>>>(Wp, whi, wlo, (float*)ws, K);
  gemm_router<<<dim3((int)(M/TOKB)), dim3(512), 0, stream>>>(hp, whi, wlo, bp, outp,
                                                             imp8, cnt8, flagCnt, flagList,
                                                             K, M, tiles);
  fixup_aux<<<dim3(128), dim3(256), 0, stream>>>(hp, Wp, bp, outp, flagCnt, flagList,
                                                 imp8, cnt8, auxp, (float)E/(float)M, K);
}

// Round 4
// 102.382 us; speedup vs baseline: 1.2703x; 1.2703x over previous
//
#include <hip/hip_runtime.h>
#include <hip/hip_bf16.h>
#include <math.h>

typedef __attribute__((ext_vector_type(8))) short  short8;
typedef __attribute__((ext_vector_type(4))) float  float4v;

#define NE 64
#define FLAG_CAP 8192
#define EPS_TIE 2e-4f

__device__ __forceinline__ unsigned short f2bf(float x){
  unsigned u = __float_as_uint(x);
  return (unsigned short)((u + 0x7fffu + ((u>>16)&1u)) >> 16);
}
__device__ __forceinline__ float bf2f(unsigned short h){
  return __uint_as_float(((unsigned)h)<<16);
}
__device__ __forceinline__ float warp_sum64(float v){
  #pragma unroll
  for (int off=1; off<64; off<<=1) v += __shfl_xor(v, off, 64);
  return v;
}

// ---------- kernel 1: split W into bf16 hi/lo in MFMA B-frag order (+zero stats) ----------
// frag layout: [ks][te][lane][8]; lane l -> e = te*16 + (l&15), k = ks*32 + (l>>4)*8 + j
__global__ __launch_bounds__(256) void prep_w(
    const float* __restrict__ W, unsigned short* __restrict__ whi,
    unsigned short* __restrict__ wlo, float* __restrict__ zbuf, int K)
{
  if (blockIdx.x == 0){                       // zero imp8[512]+cnt8[512]+flagCnt
    #pragma unroll
    for (int i=0;i<5;++i){
      const int idx = threadIdx.x + i*256;
      if (idx < 1025) zbuf[idx] = 0.f;
    }
  }
  const int id = blockIdx.x*256 + threadIdx.x;
  const int nfrag = (K/32)*4*64;
  if (id >= nfrag) return;
  const int lane = id & 63, te = (id>>6)&3, ks = id>>8;
  const int e  = te*16 + (lane&15);
  const int k0 = ks*32 + ((lane>>4)<<3);
  const float* src = W + (size_t)e*K + k0;
  short8 h8, l8;
  #pragma unroll
  for (int j=0;j<8;++j){
    float x = src[j];
    unsigned short hb = f2bf(x);
    h8[j] = (short)hb;
    l8[j] = (short)f2bf(x - bf2f(hb));
  }
  const size_t off = (size_t)id*8;
  *(short8*)(whi + off) = h8;
  *(short8*)(wlo + off) = l8;
}

// ---------- bf16 hi/lo conversion via packed cvt ----------
__device__ __forceinline__ void cvt8b(const float4& c, const float4& d,
                                      short8& hi, short8& lo){
  const float f[8] = {c.x,c.y,c.z,c.w,d.x,d.y,d.z,d.w};
  union { short8 s; unsigned u[4]; } H, L;
  #pragma unroll
  for (int p=0;p<4;++p){
    float2 v = make_float2(f[2*p], f[2*p+1]);
    __hip_bfloat162 hb = __float22bfloat162_rn(v);
    H.u[p] = *reinterpret_cast<unsigned*>(&hb);
    float2 back = __bfloat1622float2(hb);
    float2 res = make_float2(v.x - back.x, v.y - back.y);
    __hip_bfloat162 lb = __float22bfloat162_rn(res);
    L.u[p] = *reinterpret_cast<unsigned*>(&lb);
  }
  hi = H.s; lo = L.s;
}

#define MFMA3(AH, AL, BH, BL, ACC)                                          \
  ACC = __builtin_amdgcn_mfma_f32_16x16x32_bf16(AH, BH, ACC, 0,0,0);        \
  ACC = __builtin_amdgcn_mfma_f32_16x16x32_bf16(AH, BL, ACC, 0,0,0);        \
  ACC = __builtin_amdgcn_mfma_f32_16x16x32_bf16(AL, BH, ACC, 0,0,0);

// ---------- kernel 2: ALL-REGISTER fused GEMM + router finish ----------
// 64 tokens/block, 8 waves: wave = (tq = w>>2: 32 tokens) x (kq = w&3: K/4 range).
// A and B fragments load DIRECTLY from global to registers (A: 2xfloat4/lane/frag,
// B: prep_w layout is lane-contiguous dwordx4). NO LDS, NO barriers in the K-loop;
// one __syncthreads to combine K-partials (fixed order) + in-block finish.
__global__ __launch_bounds__(512) void gemm_router_reg(
    const float* __restrict__ hp, const unsigned short* __restrict__ whi,
    const unsigned short* __restrict__ wlo, const float* __restrict__ bp,
    float* __restrict__ outp, float* __restrict__ imp8, float* __restrict__ cnt8,
    int* __restrict__ flagCnt, int* __restrict__ flagList, int K, long M)
{
  __shared__ float part[2][4][32][64];   // 64 KB: [tq][kq][row][expert]
  __shared__ float red[2][8][64];        // 4 KB stats reduce

  const int tid = threadIdx.x;
  const int l = tid & 63, w = tid >> 6;
  const int tq = w >> 2, kq = w & 3;
  const int tok0 = blockIdx.x * 64;
  const int r16 = l & 15, kg = l >> 4;
  const int ktiles = K / 128;            // 32 tiles of BK=32 per K-quarter
  const int kbase = kq * (K/4);

  // A row pointers for the wave's 2 m-fragments (m89 layout: row=l&15, k=(l>>4)*8+j)
  const float* a0 = hp + (size_t)(tok0 + tq*32      + r16)*K + kbase + kg*8;
  const float* a1 = hp + (size_t)(tok0 + tq*32 + 16 + r16)*K + kbase + kg*8;
  const unsigned short* bh = whi + (size_t)(kq*ktiles)*2048 + (size_t)l*8;
  const unsigned short* bl = wlo + (size_t)(kq*ktiles)*2048 + (size_t)l*8;

  float4v acc[2][4];
  #pragma unroll
  for (int m=0;m<2;++m)
    #pragma unroll
    for (int te=0;te<4;++te) acc[m][te] = (float4v){0.f,0.f,0.f,0.f};

  // double-buffered register staging (named -> static indexing)
  float4 A0[2][2], A1[2][2];
  short8 Bh0[4], Bl0[4], Bh1[4], Bl1[4];

#define LOADT(S, T) {                                            \
  const float* p0 = a0 + (size_t)(T)*32;                         \
  const float* p1 = a1 + (size_t)(T)*32;                         \
  A##S[0][0] = *(const float4*)(p0);                             \
  A##S[0][1] = *(const float4*)(p0 + 4);                         \
  A##S[1][0] = *(const float4*)(p1);                             \
  A##S[1][1] = *(const float4*)(p1 + 4);                         \
  const unsigned short* pb = bh + (size_t)(T)*2048;              \
  const unsigned short* pl = bl + (size_t)(T)*2048;              \
  _Pragma("unroll")                                              \
  for (int te=0; te<4; ++te){                                    \
    Bh##S[te] = *(const short8*)(pb + te*512);                   \
    Bl##S[te] = *(const short8*)(pl + te*512);                   \
  }                                                              \
}

#define COMPUTET(S) {                                            \
  short8 Ah0, Al0, Ah1, Al1;                                     \
  cvt8b(A##S[0][0], A##S[0][1], Ah0, Al0);                       \
  cvt8b(A##S[1][0], A##S[1][1], Ah1, Al1);                       \
  _Pragma("unroll")                                              \
  for (int te=0; te<4; ++te){                                    \
    MFMA3(Ah0, Al0, Bh##S[te], Bl##S[te], acc[0][te]);           \
    MFMA3(Ah1, Al1, Bh##S[te], Bl##S[te], acc[1][te]);           \
  }                                                              \
}

  LOADT(0, 0);
  for (int t = 0; t < ktiles-2; t += 2){
    LOADT(1, t+1);
    COMPUTET(0);
    LOADT(0, t+2);
    COMPUTET(1);
  }
  LOADT(1, ktiles-1);
  COMPUTET(0);
  COMPUTET(1);

#undef LOADT
#undef COMPUTET

  // ---- write K-partials to LDS (C layout m89: col=lane&15, row=(lane>>4)*4+reg)
  #pragma unroll
  for (int m=0;m<2;++m)
    #pragma unroll
    for (int te=0;te<4;++te)
      #pragma unroll
      for (int r=0;r<4;++r)
        part[tq][kq][m*16 + (kg<<2) + r][te*16 + r16] = acc[m][te][r];
  __syncthreads();

  // ---- finish: wave w owns tokens w*8 .. w*8+7; lane = expert
  const float bias = bp[l];
  float impL = 0.f, cntL = 0.f;
  #pragma unroll 1
  for (int it=0; it<8; ++it){
    const int  tl = w*8 + it;
    const long tg = (long)tok0 + tl;
    const int  tq2 = tl >> 5, rr = tl & 31;
    // deterministic fixed-order K-partial sum
    float v = part[tq2][0][rr][l];
    v += part[tq2][1][rr][l];
    v += part[tq2][2][rr][l];
    v += part[tq2][3][rr][l];
    v += bias;
    float m1 = v; int i1 = l;
    #pragma unroll
    for (int off=1; off<64; off<<=1){
      float ov = __shfl_xor(m1, off, 64);
      int   oi = __shfl_xor(i1, off, 64);
      if (ov > m1 || (ov == m1 && oi < i1)){ m1 = ov; i1 = oi; }
    }
    float vm = (l == i1) ? -3.4e38f : v;
    float m2 = vm; int i2 = l;
    #pragma unroll
    for (int off=1; off<64; off<<=1){
      float ov = __shfl_xor(m2, off, 64);
      int   oi = __shfl_xor(i2, off, 64);
      if (ov > m2 || (ov == m2 && oi < i2)){ m2 = ov; i2 = oi; }
    }
    float vm3 = (l==i1 || l==i2) ? -3.4e38f : v;
    float m3 = vm3;
    #pragma unroll
    for (int off=1; off<64; off<<=1) m3 = fmaxf(m3, __shfl_xor(m3, off, 64));
    if ((m2 - m3) < EPS_TIE && l == 0){
      int idx = atomicAdd(flagCnt, 1);
      if (idx < FLAG_CAP) flagList[idx] = (int)tg;
    }
    const float ex = __expf(m2 - m1);
    const float s1 = 1.f / (1.f + ex);
    const float s2 = ex * s1;
    const float p = __expf(v - m1);
    const float S = warp_sum64(p);
    impL += p / S;
    const float rw = (l==i1) ? s1 : ((l==i2) ? s2 : 0.f);
    outp[(size_t)tg*NE + l] = rw;
    if (l==i1 || l==i2) cntL += 1.f;
  }
  red[0][w][l] = impL;
  red[1][w][l] = cntL;
  __syncthreads();
  if (tid < 64){
    float s = 0.f, c = 0.f;
    #pragma unroll
    for (int q=0; q<8; ++q){ s += red[0][q][tid]; c += red[1][q][tid]; }
    const int g = (blockIdx.x & 7) << 6;   // 8 banks kill atomic serialization
    atomicAdd(&imp8[g + tid], s);
    atomicAdd(&cnt8[g + tid], c);
  }
}

// ---------- kernel 3: fixup (one token per block) + aux fold (block 0) ----------
__global__ __launch_bounds__(256) void fixup_aux(
    const float* __restrict__ hp, const float* __restrict__ Wp,
    const float* __restrict__ bp, float* __restrict__ outp,
    const int* __restrict__ flagCnt, const int* __restrict__ flagList,
    const float* __restrict__ imp8, const float* __restrict__ cnt8,
    float* __restrict__ auxp, float scale, int K)
{
  __shared__ float hrow[4096];
  __shared__ float lg[NE];
  if (blockIdx.x == 0 && threadIdx.x < 64){     // aux: imp/cnt ready (prev kernel)
    float s = 0.f, c = 0.f;
    #pragma unroll
    for (int g=0; g<8; ++g){
      s += imp8[(g<<6) + threadIdx.x];
      c += cnt8[(g<<6) + threadIdx.x];
    }
    float v = s * c;
    v = warp_sum64(v);
    if (threadIdx.x == 0) auxp[0] = v * scale;
  }
  int n = *flagCnt; if (n > FLAG_CAP) n = FLAG_CAP;
  const int e   = threadIdx.x >> 2;
  const int sub = threadIdx.x & 3;
  const int lane = threadIdx.x & 63;

  for (int f = blockIdx.x; f < n; f += gridDim.x){
    const int tok = flagList[f];
    const float* hr = hp + (size_t)tok*K;
    #pragma unroll
    for (int c=0; c<4; ++c){
      const int idx = threadIdx.x*4 + c*1024;
      *(float4*)&hrow[idx] = *(const float4*)(hr + idx);
    }
    __syncthreads();
    const float* wr = Wp + (size_t)e*K;
    float s = 0.f;
    for (int it=0; it<64; ++it){
      const int k0 = it*64 + sub*16;
      #pragma unroll
      for (int u=0; u<4; ++u){
        float4 wv = *(const float4*)(wr + k0 + u*4);
        float4 hv = *(const float4*)(&hrow[k0 + u*4]);
        s = fmaf(hv.x, wv.x, s); s = fmaf(hv.y, wv.y, s);
        s = fmaf(hv.z, wv.z, s); s = fmaf(hv.w, wv.w, s);
      }
    }
    s += __shfl_xor(s, 1, 64);
    s += __shfl_xor(s, 2, 64);
    if (sub == 0) lg[e] = s + bp[e];
    __syncthreads();
    if (threadIdx.x < 64){
      const float v = lg[lane];
      float m1 = v; int i1 = lane;
      #pragma unroll
      for (int off=1; off<64; off<<=1){
        float ov = __shfl_xor(m1, off, 64);
        int   oi = __shfl_xor(i1, off, 64);
        if (ov > m1 || (ov == m1 && oi < i1)){ m1 = ov; i1 = oi; }
      }
      float vm = (lane == i1) ? -3.4e38f : v;
      float m2 = vm; int i2 = lane;
      #pragma unroll
      for (int off=1; off<64; off<<=1){
        float ov = __shfl_xor(m2, off, 64);
        int   oi = __shfl_xor(i2, off, 64);
        if (ov > m2 || (ov == m2 && oi < i2)){ m2 = ov; i2 = oi; }
      }
      const float ex = __expf(m2 - m1);
      const float s1 = 1.f / (1.f + ex);
      const float s2 = ex * s1;
      const float rw = (lane==i1) ? s1 : ((lane==i2) ? s2 : 0.f);
      outp[(size_t)tok * NE + lane] = rw;
    }
    __syncthreads();
  }
}

extern "C" void kernel_launch(void* const* d_in, const int* in_sizes, int n_in,
                              void* d_out, int out_size, void* d_ws, size_t ws_size,
                              hipStream_t stream){
  const float* hp = (const float*)d_in[0];
  const float* Wp = (const float*)d_in[1];
  const float* bp = (const float*)d_in[2];
  const int  E = in_sizes[2];               // 64
  const int  K = in_sizes[1] / E;           // 4096
  const long M = (long)in_sizes[0] / K;     // 16384

  float* outp = (float*)d_out;
  float* auxp = outp + (size_t)M * E;

  char* ws = (char*)d_ws;
  float* imp8     = (float*)(ws + 0);        // 8 x 64 f
  float* cnt8     = (float*)(ws + 2048);     // 8 x 64 f
  int*   flagCnt  = (int*)  (ws + 4096);
  int*   flagList = (int*)  (ws + 4160);     // FLAG_CAP ints
  unsigned short* whi = (unsigned short*)(ws + 65536);            // 512 KB
  unsigned short* wlo = (unsigned short*)(ws + 65536 + 524288);   // 512 KB

  const int nfragBlocks = ((K/32)*4*64 + 255)/256;

  prep_w<<<dim3(nfragBlocks), dim3(256), 0, stream>>>(Wp, whi, wlo, (float*)ws, K);
  gemm_router_reg<<<dim3((int)(M/64)), dim3(512), 0, stream>>>(hp, whi, wlo, bp, outp,
                                                               imp8, cnt8, flagCnt, flagList,
                                                               K, M);
  fixup_aux<<<dim3(128), dim3(256), 0, stream>>>(hp, Wp, bp, outp, flagCnt, flagList,
                                                 imp8, cnt8, auxp, (float)E/(float)M, K);
}